// Round 7
// baseline (838.457 us; speedup 1.0000x reference)
//
#include <hip/hip_runtime.h>
#include <hip/hip_bf16.h>

// ---------------- problem constants ----------------
#define B_  2
#define N_  8192
#define I_  32
#define E_  128
#define H_  64
#define BN_ (B_*N_)          // 16384
#define NW_ (N_/64)          // 128 u64 words per (b,i) mask row

// offsets inside the f64 weight block
#define O_W1    0        // (64,3)   192
#define O_A1    192      // (4,3)    12
#define O_B1    256      // (64,4)   256
#define O_W2    512      // (128,64) 8192
#define O_A2    8704     // (4,64)   256
#define O_B2    8960     // (128,4)  512
#define O_WP    9472     // (128,3)  384
#define O_BP    9856     // (128,)   128
#define O_WD1   9984     // (64,128) 8192
#define O_WD1T  18176    // transposed [e][k] 8192
#define O_BD1   26368    // 64
#define O_WD2   26432    // 64
#define O_BD2   26496    // 1
#define WTS_SZ  26560

typedef unsigned long long u64;

// ---------------- module-scope device state (fully rewritten every launch) -----
__device__ double g_wtsd[WTS_SZ];          // f64 weights (212 KB)
__device__ double g_ped [B_*I_*E_];        // pos_embed (f64)
__device__ double g_v1d [B_*I_*H_];        // decode hidden bias, initial
__device__ double g_v2d [B_*I_*H_];        // decode hidden bias, refined
__device__ double g_pfd [E_*BN_];          // pf[e][p]  (16 MB, e-major for coalescing)
__device__ double g_ud  [H_*BN_];          // u[k][p]   (8 MB, k-major for coalescing)
__device__ u64    g_masks[B_*I_*NW_];      // initial masks as bitwords (64 KB)

// ---------------- jax threefry2x32, key = key(42) = (0,42) ----------------
__device__ __forceinline__ unsigned rotl_(unsigned x, unsigned n){ return (x<<n)|(x>>(32u-n)); }

__device__ void threefry_42(unsigned x0, unsigned x1, unsigned* r0, unsigned* r1){
  const unsigned ks0 = 0u, ks1 = 42u, ks2 = 0x1BD11BDAu ^ 0u ^ 42u;
  x0 += ks0; x1 += ks1;
  x0+=x1; x1=rotl_(x1,13); x1^=x0;
  x0+=x1; x1=rotl_(x1,15); x1^=x0;
  x0+=x1; x1=rotl_(x1,26); x1^=x0;
  x0+=x1; x1=rotl_(x1, 6); x1^=x0;
  x0+=ks1; x1+=ks2+1u;
  x0+=x1; x1=rotl_(x1,17); x1^=x0;
  x0+=x1; x1=rotl_(x1,29); x1^=x0;
  x0+=x1; x1=rotl_(x1,16); x1^=x0;
  x0+=x1; x1=rotl_(x1,24); x1^=x0;
  x0+=ks2; x1+=ks0+2u;
  x0+=x1; x1=rotl_(x1,13); x1^=x0;
  x0+=x1; x1=rotl_(x1,15); x1^=x0;
  x0+=x1; x1=rotl_(x1,26); x1^=x0;
  x0+=x1; x1=rotl_(x1, 6); x1^=x0;
  x0+=ks0; x1+=ks1+3u;
  x0+=x1; x1=rotl_(x1,17); x1^=x0;
  x0+=x1; x1=rotl_(x1,29); x1^=x0;
  x0+=x1; x1=rotl_(x1,16); x1^=x0;
  x0+=x1; x1=rotl_(x1,24); x1^=x0;
  x0+=ks1; x1+=ks2+4u;
  x0+=x1; x1=rotl_(x1,13); x1^=x0;
  x0+=x1; x1=rotl_(x1,15); x1^=x0;
  x0+=x1; x1=rotl_(x1,26); x1^=x0;
  x0+=x1; x1=rotl_(x1, 6); x1^=x0;
  x0+=ks2; x1+=ks0+5u;
  *r0 = x0; *r1 = x1;
}

// element e of jax.random.uniform(key(42), (2,32,32), minval=1e-20, maxval=1.0)
// PARTITIONABLE threefry, bit_width=32: counter words (hi,lo) = (0, e) via
// iota_2x32_shape (no uint64 exists with x64 disabled!), PRF outputs
// (bits1, bits2), and the 32-bit random word is bits1 ^ bits2.
__device__ float jax_uniform_2048(int e){
  unsigned o0, o1;
  threefry_42(0u, (unsigned)e, &o0, &o1);
  unsigned bits = o0 ^ o1;
  float u = __uint_as_float((bits >> 9) | 0x3f800000u) - 1.0f;
  u = u + 1e-20f;
  return fmaxf(1e-20f, u);
}

// ---------------- K0: weight staging (f64) + pos_embed + v1 ----------------
__device__ void cvt_arr(double* dst, const float* src, int n, int tid, int nt){
  for (int i = tid; i < n; i += nt) dst[i] = (double)src[i];
}

__global__ void __launch_bounds__(256) prep_kernel(
    const float* __restrict__ pos_coords,
    const float* __restrict__ W1, const float* __restrict__ A1,
    const float* __restrict__ B1, const float* __restrict__ W2,
    const float* __restrict__ A2, const float* __restrict__ B2,
    const float* __restrict__ Wp, const float* __restrict__ bp,
    const float* __restrict__ Wd1,const float* __restrict__ bd1,
    const float* __restrict__ Wd2,const float* __restrict__ bd2)
{
  const int tid = threadIdx.x, nt = 256;
  double* wts = g_wtsd;
  cvt_arr(wts + O_W1,  W1,  64*3,   tid, nt);
  cvt_arr(wts + O_A1,  A1,  4*3,    tid, nt);
  cvt_arr(wts + O_B1,  B1,  64*4,   tid, nt);
  cvt_arr(wts + O_W2,  W2,  128*64, tid, nt);
  cvt_arr(wts + O_A2,  A2,  4*64,   tid, nt);
  cvt_arr(wts + O_B2,  B2,  128*4,  tid, nt);
  cvt_arr(wts + O_WP,  Wp,  128*3,  tid, nt);
  cvt_arr(wts + O_BP,  bp,  128,    tid, nt);
  cvt_arr(wts + O_WD1, Wd1, 64*128, tid, nt);
  cvt_arr(wts + O_BD1, bd1, 64,     tid, nt);
  cvt_arr(wts + O_WD2, Wd2, 64,     tid, nt);
  cvt_arr(wts + O_BD2, bd2, 1,      tid, nt);
  for (int idx = tid; idx < 64*128; idx += nt){
    int k = idx >> 7, e = idx & 127;
    wts[O_WD1T + e*64 + k] = (double)Wd1[idx];
  }
  __syncthreads();
  for (int idx = tid; idx < B_*I_*E_; idx += nt){
    int row = idx >> 7, e = idx & 127;
    double c0 = (double)pos_coords[row*3+0];
    double c1 = (double)pos_coords[row*3+1];
    double c2 = (double)pos_coords[row*3+2];
    double s = c0 * wts[O_WP + e*3+0]
             + c1 * wts[O_WP + e*3+1]
             + c2 * wts[O_WP + e*3+2];
    g_ped[idx] = s + wts[O_BP + e];
  }
  __syncthreads();
  for (int idx = tid; idx < B_*I_*H_; idx += nt){
    int row = idx >> 6, k = idx & 63;
    double s = 0.0;
    for (int e = 0; e < 128; ++e)
      s = fma(g_ped[row*128 + e], wts[O_WD1 + k*128 + e], s);
    g_v1d[idx] = s + wts[O_BD1 + k];
  }
}

// ---------------- K1: encoder (f64) -> g_pfd[e][p] + out_pf (f32) ----------------
__global__ void __launch_bounds__(256) encoderA_kernel(
    const float* __restrict__ points,
    float* __restrict__ out_pf)
{
  const int p = blockIdx.x * 256 + threadIdx.x;   // 0..16383
  const double* W1f = g_wtsd + O_W1;
  const double* A1f = g_wtsd + O_A1;
  const double* B1f = g_wtsd + O_B1;
  const double* W2f = g_wtsd + O_W2;
  const double* A2f = g_wtsd + O_A2;
  const double* B2f = g_wtsd + O_B2;

  const double x0 = (double)points[p*3+0];
  const double x1 = (double)points[p*3+1];
  const double x2 = (double)points[p*3+2];

  double a1[4];
  #pragma unroll
  for (int r = 0; r < 4; ++r)
    a1[r] = x0*A1f[r*3+0] + x1*A1f[r*3+1] + x2*A1f[r*3+2];

  double t1[64];
  #pragma unroll
  for (int k = 0; k < 64; ++k){
    double s = x0*W1f[k*3+0] + x1*W1f[k*3+1] + x2*W1f[k*3+2];
    double l = a1[0]*B1f[k*4+0] + a1[1]*B1f[k*4+1]
             + a1[2]*B1f[k*4+2] + a1[3]*B1f[k*4+3];
    double v = s + 0.25*l;
    t1[k] = v > 0.0 ? v : 0.0;
  }
  double a2[4];
  #pragma unroll
  for (int r = 0; r < 4; ++r){
    double s = 0.0;
    #pragma unroll
    for (int j = 0; j < 64; ++j) s = fma(t1[j], A2f[r*64+j], s);
    a2[r] = s;
  }
  for (int e = 0; e < 128; ++e){
    double s1 = 0.0;
    #pragma unroll
    for (int j = 0; j < 64; ++j) s1 = fma(t1[j], W2f[e*64+j], s1);
    double s2 = a2[0]*B2f[e*4+0] + a2[1]*B2f[e*4+1]
              + a2[2]*B2f[e*4+2] + a2[3]*B2f[e*4+3];
    const double pf = s1 + 0.25*s2;
    g_pfd[(size_t)e * BN_ + p] = pf;                 // e-major: coalesced
    out_pf[(size_t)p * E_ + e] = (float)pf;          // required [B,N,E] layout
  }
}

// ---------------- K2: u[k][p] = sum_e pf[e][p] * Wd1[k][e] ----------------
__global__ void __launch_bounds__(256) uacc_kernel()
{
  const int p = blockIdx.x * 256 + threadIdx.x;
  const double* Wd1T = g_wtsd + O_WD1T;     // [e][k]
  double u[64];
  #pragma unroll
  for (int k = 0; k < 64; ++k) u[k] = 0.0;
  for (int e = 0; e < 128; ++e){
    const double pf = g_pfd[(size_t)e * BN_ + p];
    #pragma unroll
    for (int k = 0; k < 64; ++k)
      u[k] = fma(pf, Wd1T[e*64 + k], u[k]);
  }
  #pragma unroll
  for (int k = 0; k < 64; ++k)
    g_ud[(size_t)k * BN_ + p] = u[k];
}

// ---------------- K3/K5: decode ----------------
template<bool INITIAL>
__global__ void __launch_bounds__(256) decode_kernel(float* __restrict__ out0)
{
  const int tid  = threadIdx.x;
  const int w_u  = __builtin_amdgcn_readfirstlane(tid >> 6);
  const int lane = tid & 63;
  const int bc   = blockIdx.x;           // 256 blocks
  const int b    = bc >> 7;
  const int nb   = (bc & 127) << 6;
  const int n    = nb + lane;
  const int p    = b * N_ + n;

  double u[64];
  #pragma unroll
  for (int k = 0; k < 64; ++k) u[k] = g_ud[(size_t)k * BN_ + p];

  const double* wd2 = g_wtsd + O_WD2;
  const double  bd2v = g_wtsd[O_BD2];
  const double* vbase = INITIAL ? g_v1d : g_v2d;

  for (int ii = 0; ii < 8; ++ii){
    const int i = w_u * 8 + ii;                       // wave-uniform
    const double* v = vbase + ((b * I_ + i) << 6);
    double acc = 0.0;
    #pragma unroll
    for (int k = 0; k < 64; ++k){
      double h = u[k] + v[k];
      h = h > 0.0 ? h : 0.0;
      acc = fma(wd2[k], h, acc);
    }
    const double logit = acc + bd2v;
    if (INITIAL){
      u64 bal = __ballot(logit > 0.0);
      if (lane == 0) g_masks[(size_t)(b * I_ + i) * NW_ + (nb >> 6)] = bal;
    } else {
      out0[(size_t)(b * I_ + i) * N_ + n] = (float)logit;
    }
  }
}

// ---------------- K4: IoU (f32-exact mimicry) + Gumbel-max (f32) + v2 ----------------
__global__ void __launch_bounds__(256) sample_kernel(
    const float* __restrict__ pos_coords)
{
  __shared__ int    msum_l[64];
  __shared__ int    inter_l[2048];
  __shared__ double delta_l[64*129];
  const int tid = threadIdx.x;

  if (tid < 64){
    const u64* m = g_masks + (size_t)tid * NW_;
    int s = 0;
    for (int ww = 0; ww < NW_; ++ww) s += __popcll(m[ww]);
    msum_l[tid] = s;
  }
  for (int pair = tid; pair < 2048; pair += 256){
    const int b = pair >> 10, ij = pair & 1023, i = ij >> 5, j = ij & 31;
    const u64* mi = g_masks + (size_t)(b*32 + i) * NW_;
    const u64* mj = g_masks + (size_t)(b*32 + j) * NW_;
    int s = 0;
    for (int ww = 0; ww < NW_; ++ww) s += __popcll(mi[ww] & mj[ww]);
    inter_l[pair] = s;
  }
  __syncthreads();

  if (tid < 64){
    const int b = tid >> 5;
    const int i = tid & 31;
    float best = -INFINITY; int bestj = 0; bool any = false;
    for (int j = 0; j < 32; ++j){
      const int inter = inter_l[(b << 10) + (i << 5) + j];
      const int uni   = msum_l[(b << 5) + i] + msum_l[(b << 5) + j] - inter;
      // EXACT f32 mimicry of the reference: inter/(union+1e-6) in f32.
      const float iou = (float)inter / ((float)uni + 1e-6f);
      const bool cand = (j != i) && (iou >= 0.1f);
      if (cand){
        any = true;
        const float uu = jax_uniform_2048((tid << 5) + j);
        const float g  = -logf(-logf(uu));           // f32, like the ref
        if (g > best){ best = g; bestj = j; }        // first-max like argmax
      }
    }
    double nc0 = 0.0, nc1 = 0.0, nc2 = 0.0;
    if (any){
      nc0 = (double)pos_coords[(b*32 + bestj)*3 + 0];
      nc1 = (double)pos_coords[(b*32 + bestj)*3 + 1];
      nc2 = (double)pos_coords[(b*32 + bestj)*3 + 2];
    }
    for (int e = 0; e < 128; ++e){
      double ne = nc0 * g_wtsd[O_WP + e*3+0]
                + nc1 * g_wtsd[O_WP + e*3+1]
                + nc2 * g_wtsd[O_WP + e*3+2]
                + g_wtsd[O_BP + e];
      delta_l[tid*129 + e] = g_ped[tid*128 + e] - ne;
    }
  }
  __syncthreads();

  for (int idx = tid; idx < B_*I_*H_; idx += 256){
    const int row = idx >> 6, k = idx & 63;
    double s = 0.0;
    for (int e = 0; e < 128; ++e)
      s = fma(delta_l[row*129 + e], g_wtsd[O_WD1 + k*128 + e], s);
    g_v2d[idx] = s + g_wtsd[O_BD1 + k];
  }
}

// ---------------- launch ----------------
extern "C" void kernel_launch(void* const* d_in, const int* in_sizes, int n_in,
                              void* d_out, int out_size, void* d_ws, size_t ws_size,
                              hipStream_t stream)
{
  (void)in_sizes; (void)n_in; (void)out_size; (void)d_ws; (void)ws_size;
  const float* points     = (const float*)d_in[0];
  const float* pos_coords = (const float*)d_in[1];
  const float* W1  = (const float*)d_in[2];
  const float* A1  = (const float*)d_in[3];
  const float* B1  = (const float*)d_in[4];
  const float* W2  = (const float*)d_in[5];
  const float* A2  = (const float*)d_in[6];
  const float* B2  = (const float*)d_in[7];
  const float* Wp  = (const float*)d_in[8];
  const float* bp  = (const float*)d_in[9];
  const float* Wd1 = (const float*)d_in[10];
  const float* bd1 = (const float*)d_in[11];
  const float* Wd2 = (const float*)d_in[12];
  const float* bd2 = (const float*)d_in[13];

  float* out0   = (float*)d_out;                        // refined_logits [B,I,N]
  float* out_pf = out0 + (size_t)B_ * I_ * N_;          // point_feats   [B,N,E]

  prep_kernel<<<1, 256, 0, stream>>>(pos_coords, W1, A1, B1, W2, A2, B2,
                                     Wp, bp, Wd1, bd1, Wd2, bd2);
  encoderA_kernel<<<64, 256, 0, stream>>>(points, out_pf);
  uacc_kernel<<<64, 256, 0, stream>>>();
  decode_kernel<true><<<256, 256, 0, stream>>>(nullptr);
  sample_kernel<<<1, 256, 0, stream>>>(pos_coords);
  decode_kernel<false><<<256, 256, 0, stream>>>(out0);
}

// Round 8
// 360.324 us; speedup vs baseline: 2.3269x; 2.3269x over previous
//
#include <hip/hip_runtime.h>

// ---------------- problem constants ----------------
#define B_  2
#define N_  8192
#define I_  32
#define E_  128
#define H_  64
#define BN_ (B_*N_)          // 16384
#define NW_ (N_/64)          // 128 u64 words per (b,i) mask row

typedef unsigned long long u64;

// ---------------- module-scope device state (fully rewritten every launch) -----
__device__ float g_pe  [B_*I_*E_];     // pos_embed
__device__ float g_v1  [B_*I_*H_];     // decode hidden bias, initial
__device__ float g_v2  [B_*I_*H_];     // decode hidden bias, refined
__device__ float g_wd1t[E_*H_];        // Wd1 transposed [e][k]
__device__ float g_u   [H_*BN_];       // u[k][p] (4 MB, k-major -> coalesced)
__device__ u64   g_masks[B_*I_*NW_];   // initial masks as bitwords (64 KB)

// ---------------- jax threefry2x32, key = key(42) = (0,42) ----------------
__device__ __forceinline__ unsigned rotl_(unsigned x, unsigned n){ return (x<<n)|(x>>(32u-n)); }

__device__ void threefry_42(unsigned x0, unsigned x1, unsigned* r0, unsigned* r1){
  const unsigned ks0 = 0u, ks1 = 42u, ks2 = 0x1BD11BDAu ^ 0u ^ 42u;
  x0 += ks0; x1 += ks1;
  x0+=x1; x1=rotl_(x1,13); x1^=x0;
  x0+=x1; x1=rotl_(x1,15); x1^=x0;
  x0+=x1; x1=rotl_(x1,26); x1^=x0;
  x0+=x1; x1=rotl_(x1, 6); x1^=x0;
  x0+=ks1; x1+=ks2+1u;
  x0+=x1; x1=rotl_(x1,17); x1^=x0;
  x0+=x1; x1=rotl_(x1,29); x1^=x0;
  x0+=x1; x1=rotl_(x1,16); x1^=x0;
  x0+=x1; x1=rotl_(x1,24); x1^=x0;
  x0+=ks2; x1+=ks0+2u;
  x0+=x1; x1=rotl_(x1,13); x1^=x0;
  x0+=x1; x1=rotl_(x1,15); x1^=x0;
  x0+=x1; x1=rotl_(x1,26); x1^=x0;
  x0+=x1; x1=rotl_(x1, 6); x1^=x0;
  x0+=ks0; x1+=ks1+3u;
  x0+=x1; x1=rotl_(x1,17); x1^=x0;
  x0+=x1; x1=rotl_(x1,29); x1^=x0;
  x0+=x1; x1=rotl_(x1,16); x1^=x0;
  x0+=x1; x1=rotl_(x1,24); x1^=x0;
  x0+=ks1; x1+=ks2+4u;
  x0+=x1; x1=rotl_(x1,13); x1^=x0;
  x0+=x1; x1=rotl_(x1,15); x1^=x0;
  x0+=x1; x1=rotl_(x1,26); x1^=x0;
  x0+=x1; x1=rotl_(x1, 6); x1^=x0;
  x0+=ks2; x1+=ks0+5u;
  *r0 = x0; *r1 = x1;
}

// element e of jax.random.uniform(key(42), (2,32,32), 1e-20, 1.0)
// PARTITIONABLE threefry (VERIFIED r7): counter (0,e), bits = out0 ^ out1.
__device__ float jax_uniform_2048(int e){
  unsigned o0, o1;
  threefry_42(0u, (unsigned)e, &o0, &o1);
  unsigned bits = o0 ^ o1;
  float u = __uint_as_float((bits >> 9) | 0x3f800000u) - 1.0f;
  u = u + 1e-20f;
  return fmaxf(1e-20f, u);
}

// ---------------- K0: pos_embed + v1 + Wd1^T (1 block) ----------------
__global__ void __launch_bounds__(256) prep_kernel(
    const float* __restrict__ pos_coords,
    const float* __restrict__ Wp, const float* __restrict__ bp,
    const float* __restrict__ Wd1,const float* __restrict__ bd1)
{
  const int tid = threadIdx.x;
  for (int idx = tid; idx < B_*I_*E_; idx += 256){
    int row = idx >> 7, e = idx & 127;
    float s = pos_coords[row*3+0] * Wp[e*3+0];
    s = fmaf(pos_coords[row*3+1], Wp[e*3+1], s);
    s = fmaf(pos_coords[row*3+2], Wp[e*3+2], s);
    g_pe[idx] = s + bp[e];
  }
  for (int idx = tid; idx < E_*H_; idx += 256){
    int e = idx >> 6, k = idx & 63;
    g_wd1t[idx] = Wd1[k*128 + e];
  }
  __syncthreads();
  for (int idx = tid; idx < B_*I_*H_; idx += 256){
    int row = idx >> 6, k = idx & 63;
    float s = 0.f;
    for (int e = 0; e < 128; ++e)
      s = fmaf(g_pe[row*128 + e], Wd1[k*128 + e], s);
    g_v1[idx] = s + bd1[k];
  }
}

// ---------------- K1: FUSED encoder + u + initial ballot ----------------
// 256 blocks x 256 threads; block = 64 consecutive points; wave w owns e-range
__global__ void __launch_bounds__(256) enc_kernel(
    const float* __restrict__ points,
    const float* __restrict__ W1, const float* __restrict__ A1,
    const float* __restrict__ B1, const float* __restrict__ W2,
    const float* __restrict__ A2, const float* __restrict__ B2,
    const float* __restrict__ Wd2,const float* __restrict__ bd2,
    float* __restrict__ out_pf)
{
  __shared__ float pf_l[E_*65];      // [e][point], padded: 33.3 KB
  __shared__ float u_l [64*65];      // [point][k], padded: 16.6 KB
  const int tid  = threadIdx.x;
  const int w_u  = __builtin_amdgcn_readfirstlane(tid >> 6);
  const int lane = tid & 63;
  const int p0   = blockIdx.x * 64;
  const int p    = p0 + lane;
  const int b    = blockIdx.x >> 7;            // 128 blocks per batch

  const float x0 = points[p*3+0];
  const float x1 = points[p*3+1];
  const float x2 = points[p*3+2];

  float a1[4];
  #pragma unroll
  for (int r = 0; r < 4; ++r){
    float s = x0 * A1[r*3+0];
    s = fmaf(x1, A1[r*3+1], s);
    s = fmaf(x2, A1[r*3+2], s);
    a1[r] = s;
  }
  float t1[64];
  #pragma unroll
  for (int k = 0; k < 64; ++k){
    float s = x0 * W1[k*3+0];
    s = fmaf(x1, W1[k*3+1], s);
    s = fmaf(x2, W1[k*3+2], s);
    float l = a1[0] * B1[k*4+0];
    l = fmaf(a1[1], B1[k*4+1], l);
    l = fmaf(a1[2], B1[k*4+2], l);
    l = fmaf(a1[3], B1[k*4+3], l);
    t1[k] = fmaxf(fmaf(0.25f, l, s), 0.0f);
  }
  float a2[4];
  #pragma unroll
  for (int r = 0; r < 4; ++r){
    float s = 0.f;
    #pragma unroll
    for (int j = 0; j < 64; ++j) s = fmaf(t1[j], A2[r*64+j], s);
    a2[r] = s;
  }
  float u_p[64];
  #pragma unroll
  for (int k = 0; k < 64; ++k) u_p[k] = 0.f;

  for (int ei = 0; ei < 32; ++ei){
    const int e = w_u * 32 + ei;               // wave-uniform -> scalar loads
    float s1 = 0.f;
    #pragma unroll
    for (int j = 0; j < 64; ++j) s1 = fmaf(t1[j], W2[e*64+j], s1);
    float s2 = a2[0] * B2[e*4+0];
    s2 = fmaf(a2[1], B2[e*4+1], s2);
    s2 = fmaf(a2[2], B2[e*4+2], s2);
    s2 = fmaf(a2[3], B2[e*4+3], s2);
    const float pf = fmaf(0.25f, s2, s1);
    pf_l[e*65 + lane] = pf;                    // bank = lane%32: conflict-free
    #pragma unroll
    for (int k = 0; k < 64; ++k) u_p[k] = fmaf(pf, g_wd1t[e*64+k], u_p[k]);
  }
  __syncthreads();

  // coalesced pf store: consecutive idx -> consecutive global addresses
  for (int idx = tid; idx < 64*E_; idx += 256){
    const int pt = idx >> 7, e = idx & 127;
    out_pf[(size_t)p0 * E_ + idx] = pf_l[e*65 + pt];   // = out_pf[(p0+pt)*128+e]
  }

  // staged reduction of the 4 e-range partials into u_l[point][k]
  for (int pass = 0; pass < 4; ++pass){
    if (w_u == pass){
      if (pass == 0){
        #pragma unroll
        for (int k = 0; k < 64; ++k) u_l[lane*65 + k] = u_p[k];
      } else {
        #pragma unroll
        for (int k = 0; k < 64; ++k) u_l[lane*65 + k] += u_p[k];
      }
    }
    __syncthreads();
  }

  // coalesced u store: k-major
  for (int idx = tid; idx < 64*64; idx += 256){
    const int k = idx >> 6, pl = idx & 63;
    g_u[(size_t)k * BN_ + p0 + pl] = u_l[pl*65 + k];
  }

  // fused initial decode + ballot (lane = point within 64-chunk = bit index)
  const float bd2v = bd2[0];
  for (int ii = 0; ii < 8; ++ii){
    const int i = w_u * 8 + ii;                          // wave-uniform
    const float* v = g_v1 + ((b * I_ + i) << 6);
    float acc = 0.f;
    #pragma unroll
    for (int k = 0; k < 64; ++k)
      acc = fmaf(Wd2[k], fmaxf(u_l[lane*65 + k] + v[k], 0.0f), acc);
    const float logit = acc + bd2v;
    u64 bal = __ballot(logit > 0.0f);
    if (lane == 0) g_masks[(size_t)(b * I_ + i) * NW_ + (blockIdx.x & 127)] = bal;
  }
}

// ---------------- K2: IoU (f32-exact mimicry) + Gumbel-max + v2 ----------------
__global__ void __launch_bounds__(256) sample_kernel(
    const float* __restrict__ pos_coords,
    const float* __restrict__ Wp, const float* __restrict__ bp,
    const float* __restrict__ Wd1,const float* __restrict__ bd1)
{
  __shared__ int   msum_l[64];
  __shared__ int   inter_l[2048];
  __shared__ float delta_l[64*129];
  const int tid = threadIdx.x;

  if (tid < 64){
    const u64* m = g_masks + (size_t)tid * NW_;
    int s = 0;
    for (int ww = 0; ww < NW_; ++ww) s += __popcll(m[ww]);
    msum_l[tid] = s;
  }
  for (int pair = tid; pair < 2048; pair += 256){
    const int b = pair >> 10, ij = pair & 1023, i = ij >> 5, j = ij & 31;
    const u64* mi = g_masks + (size_t)(b*32 + i) * NW_;
    const u64* mj = g_masks + (size_t)(b*32 + j) * NW_;
    int s = 0;
    for (int ww = 0; ww < NW_; ++ww) s += __popcll(mi[ww] & mj[ww]);
    inter_l[pair] = s;
  }
  __syncthreads();

  if (tid < 64){
    const int b = tid >> 5;
    const int i = tid & 31;
    float best = -INFINITY; int bestj = 0; bool any = false;
    for (int j = 0; j < 32; ++j){
      const int inter = inter_l[(b << 10) + (i << 5) + j];
      const int uni   = msum_l[(b << 5) + i] + msum_l[(b << 5) + j] - inter;
      // EXACT f32 mimicry of the reference: inter/(union+1e-6) in f32.
      const float iou = (float)inter / ((float)uni + 1e-6f);
      const bool cand = (j != i) && (iou >= 0.1f);
      if (cand){
        any = true;
        const float uu = jax_uniform_2048((tid << 5) + j);
        const float g  = -logf(-logf(uu));
        if (g > best){ best = g; bestj = j; }            // first-max like argmax
      }
    }
    float nc0 = 0.f, nc1 = 0.f, nc2 = 0.f;
    if (any){
      nc0 = pos_coords[(b*32 + bestj)*3 + 0];
      nc1 = pos_coords[(b*32 + bestj)*3 + 1];
      nc2 = pos_coords[(b*32 + bestj)*3 + 2];
    }
    for (int e = 0; e < 128; ++e){
      float ne = nc0 * Wp[e*3+0];
      ne = fmaf(nc1, Wp[e*3+1], ne);
      ne = fmaf(nc2, Wp[e*3+2], ne);
      ne = ne + bp[e];                                   // == bp when invalid
      delta_l[tid*129 + e] = g_pe[tid*128 + e] - ne;
    }
  }
  __syncthreads();

  for (int idx = tid; idx < B_*I_*H_; idx += 256){
    const int row = idx >> 6, k = idx & 63;
    float s = 0.f;
    for (int e = 0; e < 128; ++e)
      s = fmaf(delta_l[row*129 + e], Wd1[k*128 + e], s);
    g_v2[idx] = s + bd1[k];
  }
}

// ---------------- K3: refined decode ----------------
__global__ void __launch_bounds__(256) dec_kernel(
    const float* __restrict__ Wd2, const float* __restrict__ bd2,
    float* __restrict__ out0)
{
  const int tid  = threadIdx.x;
  const int w_u  = __builtin_amdgcn_readfirstlane(tid >> 6);
  const int lane = tid & 63;
  const int bc   = blockIdx.x;           // 256 blocks
  const int b    = bc >> 7;
  const int nb   = (bc & 127) << 6;
  const int n    = nb + lane;
  const int p    = b * N_ + n;

  float u[64];
  #pragma unroll
  for (int k = 0; k < 64; ++k) u[k] = g_u[(size_t)k * BN_ + p];   // coalesced

  const float bd2v = bd2[0];
  for (int ii = 0; ii < 8; ++ii){
    const int i = w_u * 8 + ii;                       // wave-uniform
    const float* v = g_v2 + ((b * I_ + i) << 6);
    float acc = 0.f;
    #pragma unroll
    for (int k = 0; k < 64; ++k)
      acc = fmaf(Wd2[k], fmaxf(u[k] + v[k], 0.0f), acc);
    out0[(size_t)(b * I_ + i) * N_ + n] = acc + bd2v;
  }
}

// ---------------- launch ----------------
extern "C" void kernel_launch(void* const* d_in, const int* in_sizes, int n_in,
                              void* d_out, int out_size, void* d_ws, size_t ws_size,
                              hipStream_t stream)
{
  (void)in_sizes; (void)n_in; (void)out_size; (void)d_ws; (void)ws_size;
  const float* points     = (const float*)d_in[0];
  const float* pos_coords = (const float*)d_in[1];
  const float* W1  = (const float*)d_in[2];
  const float* A1  = (const float*)d_in[3];
  const float* B1  = (const float*)d_in[4];
  const float* W2  = (const float*)d_in[5];
  const float* A2  = (const float*)d_in[6];
  const float* B2  = (const float*)d_in[7];
  const float* Wp  = (const float*)d_in[8];
  const float* bp  = (const float*)d_in[9];
  const float* Wd1 = (const float*)d_in[10];
  const float* bd1 = (const float*)d_in[11];
  const float* Wd2 = (const float*)d_in[12];
  const float* bd2 = (const float*)d_in[13];

  float* out0   = (float*)d_out;                        // refined_logits [B,I,N]
  float* out_pf = out0 + (size_t)B_ * I_ * N_;          // point_feats   [B,N,E]

  prep_kernel<<<1, 256, 0, stream>>>(pos_coords, Wp, bp, Wd1, bd1);
  enc_kernel<<<256, 256, 0, stream>>>(points, W1, A1, B1, W2, A2, B2,
                                      Wd2, bd2, out_pf);
  sample_kernel<<<1, 256, 0, stream>>>(pos_coords, Wp, bp, Wd1, bd1);
  dec_kernel<<<256, 256, 0, stream>>>(Wd2, bd2, out0);
}

// Round 9
// 297.349 us; speedup vs baseline: 2.8198x; 1.2118x over previous
//
#include <hip/hip_runtime.h>

// ---------------- problem constants ----------------
#define B_  2
#define N_  8192
#define I_  32
#define E_  128
#define H_  64
#define BN_ (B_*N_)          // 16384
#define NW_ (N_/64)          // 128 u64 words per (b,i) mask row

typedef unsigned long long u64;

// ---------------- module-scope device state (fully rewritten every launch) -----
__device__ float g_pe  [B_*I_*E_];     // pos_embed
__device__ float g_v1  [B_*I_*H_];     // decode hidden bias, initial
__device__ float g_v2  [B_*I_*H_];     // decode hidden bias, refined
__device__ float g_wd1t[E_*H_];        // Wd1 transposed [e][k]
__device__ float g_u   [H_*BN_];       // u[k][p] (4 MB, k-major -> coalesced)
__device__ u64   g_masks[B_*I_*NW_];   // initial masks as bitwords (64 KB)
__device__ int   g_inter[B_*I_*I_];    // intersection counts (diag = m_sum)

// ---------------- jax threefry2x32, key = key(42) = (0,42) ----------------
__device__ __forceinline__ unsigned rotl_(unsigned x, unsigned n){ return (x<<n)|(x>>(32u-n)); }

__device__ void threefry_42(unsigned x0, unsigned x1, unsigned* r0, unsigned* r1){
  const unsigned ks0 = 0u, ks1 = 42u, ks2 = 0x1BD11BDAu ^ 0u ^ 42u;
  x0 += ks0; x1 += ks1;
  x0+=x1; x1=rotl_(x1,13); x1^=x0;
  x0+=x1; x1=rotl_(x1,15); x1^=x0;
  x0+=x1; x1=rotl_(x1,26); x1^=x0;
  x0+=x1; x1=rotl_(x1, 6); x1^=x0;
  x0+=ks1; x1+=ks2+1u;
  x0+=x1; x1=rotl_(x1,17); x1^=x0;
  x0+=x1; x1=rotl_(x1,29); x1^=x0;
  x0+=x1; x1=rotl_(x1,16); x1^=x0;
  x0+=x1; x1=rotl_(x1,24); x1^=x0;
  x0+=ks2; x1+=ks0+2u;
  x0+=x1; x1=rotl_(x1,13); x1^=x0;
  x0+=x1; x1=rotl_(x1,15); x1^=x0;
  x0+=x1; x1=rotl_(x1,26); x1^=x0;
  x0+=x1; x1=rotl_(x1, 6); x1^=x0;
  x0+=ks0; x1+=ks1+3u;
  x0+=x1; x1=rotl_(x1,17); x1^=x0;
  x0+=x1; x1=rotl_(x1,29); x1^=x0;
  x0+=x1; x1=rotl_(x1,16); x1^=x0;
  x0+=x1; x1=rotl_(x1,24); x1^=x0;
  x0+=ks1; x1+=ks2+4u;
  x0+=x1; x1=rotl_(x1,13); x1^=x0;
  x0+=x1; x1=rotl_(x1,15); x1^=x0;
  x0+=x1; x1=rotl_(x1,26); x1^=x0;
  x0+=x1; x1=rotl_(x1, 6); x1^=x0;
  x0+=ks2; x1+=ks0+5u;
  *r0 = x0; *r1 = x1;
}

// element e of jax.random.uniform(key(42), (2,32,32), 1e-20, 1.0)
// PARTITIONABLE threefry (VERIFIED r7): counter (0,e), bits = out0 ^ out1.
__device__ float jax_uniform_2048(int e){
  unsigned o0, o1;
  threefry_42(0u, (unsigned)e, &o0, &o1);
  unsigned bits = o0 ^ o1;
  float u = __uint_as_float((bits >> 9) | 0x3f800000u) - 1.0f;
  u = u + 1e-20f;
  return fmaxf(1e-20f, u);
}

// ---------------- K0: pos_embed + v1 + Wd1^T (1 block) ----------------
__global__ void __launch_bounds__(256) prep_kernel(
    const float* __restrict__ pos_coords,
    const float* __restrict__ Wp, const float* __restrict__ bp,
    const float* __restrict__ Wd1,const float* __restrict__ bd1)
{
  const int tid = threadIdx.x;
  for (int idx = tid; idx < B_*I_*E_; idx += 256){
    int row = idx >> 7, e = idx & 127;
    float s = pos_coords[row*3+0] * Wp[e*3+0];
    s = fmaf(pos_coords[row*3+1], Wp[e*3+1], s);
    s = fmaf(pos_coords[row*3+2], Wp[e*3+2], s);
    g_pe[idx] = s + bp[e];
  }
  for (int idx = tid; idx < E_*H_; idx += 256){
    int e = idx >> 6, k = idx & 63;
    g_wd1t[idx] = Wd1[k*128 + e];
  }
  __syncthreads();
  for (int idx = tid; idx < B_*I_*H_; idx += 256){
    int row = idx >> 6, k = idx & 63;
    float s = 0.f;
    for (int e = 0; e < 128; ++e)
      s = fmaf(g_pe[row*128 + e], Wd1[k*128 + e], s);
    g_v1[idx] = s + bd1[k];
  }
}

// ---------------- K1: FUSED encoder + u + initial ballot ----------------
// 256 blocks x 256 threads; block = 64 consecutive points; wave w owns e-range
__global__ void __launch_bounds__(256) enc_kernel(
    const float* __restrict__ points,
    const float* __restrict__ W1, const float* __restrict__ A1,
    const float* __restrict__ B1, const float* __restrict__ W2,
    const float* __restrict__ A2, const float* __restrict__ B2,
    const float* __restrict__ Wd2,const float* __restrict__ bd2,
    float* __restrict__ out_pf)
{
  __shared__ float pf_l[E_*65];      // [e][point], padded: 33.3 KB
  __shared__ float u_l [64*65];      // [point][k], padded: 16.6 KB
  const int tid  = threadIdx.x;
  const int w_u  = __builtin_amdgcn_readfirstlane(tid >> 6);
  const int lane = tid & 63;
  const int p0   = blockIdx.x * 64;
  const int p    = p0 + lane;
  const int b    = blockIdx.x >> 7;            // 128 blocks per batch

  const float x0 = points[p*3+0];
  const float x1 = points[p*3+1];
  const float x2 = points[p*3+2];

  float a1[4];
  #pragma unroll
  for (int r = 0; r < 4; ++r){
    float s = x0 * A1[r*3+0];
    s = fmaf(x1, A1[r*3+1], s);
    s = fmaf(x2, A1[r*3+2], s);
    a1[r] = s;
  }
  float t1[64];
  #pragma unroll
  for (int k = 0; k < 64; ++k){
    float s = x0 * W1[k*3+0];
    s = fmaf(x1, W1[k*3+1], s);
    s = fmaf(x2, W1[k*3+2], s);
    float l = a1[0] * B1[k*4+0];
    l = fmaf(a1[1], B1[k*4+1], l);
    l = fmaf(a1[2], B1[k*4+2], l);
    l = fmaf(a1[3], B1[k*4+3], l);
    t1[k] = fmaxf(fmaf(0.25f, l, s), 0.0f);
  }
  float a2[4];
  #pragma unroll
  for (int r = 0; r < 4; ++r){
    float s = 0.f;
    #pragma unroll
    for (int j = 0; j < 64; ++j) s = fmaf(t1[j], A2[r*64+j], s);
    a2[r] = s;
  }
  float u_p[64];
  #pragma unroll
  for (int k = 0; k < 64; ++k) u_p[k] = 0.f;

  for (int ei = 0; ei < 32; ++ei){
    const int e = w_u * 32 + ei;               // wave-uniform -> scalar loads
    float s1 = 0.f;
    #pragma unroll
    for (int j = 0; j < 64; ++j) s1 = fmaf(t1[j], W2[e*64+j], s1);
    float s2 = a2[0] * B2[e*4+0];
    s2 = fmaf(a2[1], B2[e*4+1], s2);
    s2 = fmaf(a2[2], B2[e*4+2], s2);
    s2 = fmaf(a2[3], B2[e*4+3], s2);
    const float pf = fmaf(0.25f, s2, s1);
    pf_l[e*65 + lane] = pf;                    // bank = lane%32: conflict-free
    #pragma unroll
    for (int k = 0; k < 64; ++k) u_p[k] = fmaf(pf, g_wd1t[e*64+k], u_p[k]);
  }
  __syncthreads();

  // coalesced pf store
  for (int idx = tid; idx < 64*E_; idx += 256){
    const int pt = idx >> 7, e = idx & 127;
    out_pf[(size_t)p0 * E_ + idx] = pf_l[e*65 + pt];
  }

  // staged reduction of the 4 e-range partials into u_l[point][k]
  for (int pass = 0; pass < 4; ++pass){
    if (w_u == pass){
      if (pass == 0){
        #pragma unroll
        for (int k = 0; k < 64; ++k) u_l[lane*65 + k] = u_p[k];
      } else {
        #pragma unroll
        for (int k = 0; k < 64; ++k) u_l[lane*65 + k] += u_p[k];
      }
    }
    __syncthreads();
  }

  // coalesced u store: k-major
  for (int idx = tid; idx < 64*64; idx += 256){
    const int k = idx >> 6, pl = idx & 63;
    g_u[(size_t)k * BN_ + p0 + pl] = u_l[pl*65 + k];
  }

  // fused initial decode + ballot
  const float bd2v = bd2[0];
  for (int ii = 0; ii < 8; ++ii){
    const int i = w_u * 8 + ii;                          // wave-uniform
    const float* v = g_v1 + ((b * I_ + i) << 6);
    float acc = 0.f;
    #pragma unroll
    for (int k = 0; k < 64; ++k)
      acc = fmaf(Wd2[k], fmaxf(u_l[lane*65 + k] + v[k], 0.0f), acc);
    const float logit = acc + bd2v;
    u64 bal = __ballot(logit > 0.0f);
    if (lane == 0) g_masks[(size_t)(b * I_ + i) * NW_ + (blockIdx.x & 127)] = bal;
  }
}

// ---------------- K2a: inter[r][j] = popcount(m_r & m_j), 64 blocks ----------------
// block = row r (b*32+i); 8 threads per j, 16 u64 words each; shuffle-reduce.
__global__ void __launch_bounds__(256) inter_kernel()
{
  const int r   = blockIdx.x;          // 0..63
  const int b   = r >> 5;
  const int tid = threadIdx.x;
  const int j   = tid >> 3;            // 0..31
  const int ws  = (tid & 7) * 16;      // word segment base
  const u64* mi = g_masks + (size_t)r * NW_;
  const u64* mj = g_masks + (size_t)(b*32 + j) * NW_;
  int s = 0;
  #pragma unroll
  for (int w = 0; w < 16; ++w)
    s += __popcll(mi[ws + w] & mj[ws + w]);
  s += __shfl_xor(s, 1, 64);
  s += __shfl_xor(s, 2, 64);
  s += __shfl_xor(s, 4, 64);
  if ((tid & 7) == 0) g_inter[r*32 + j] = s;
}

// ---------------- K2b: Gumbel-max sampling + v2 (1 block) ----------------
__global__ void __launch_bounds__(256) sample_kernel(
    const float* __restrict__ pos_coords,
    const float* __restrict__ Wp, const float* __restrict__ bp,
    const float* __restrict__ Wd1,const float* __restrict__ bd1)
{
  __shared__ int   inter_l[2048];
  __shared__ float delta_l[64*129];
  const int tid = threadIdx.x;

  for (int idx = tid; idx < 2048; idx += 256) inter_l[idx] = g_inter[idx];
  __syncthreads();

  if (tid < 64){
    const int b = tid >> 5;
    const int i = tid & 31;
    const int msum_i = inter_l[(b << 10) + (i << 5) + i];   // diag = m_sum
    float best = -INFINITY; int bestj = 0; bool any = false;
    for (int j = 0; j < 32; ++j){
      const int inter = inter_l[(b << 10) + (i << 5) + j];
      const int msum_j = inter_l[(b << 10) + (j << 5) + j];
      const int uni   = msum_i + msum_j - inter;
      // EXACT f32 mimicry of the reference: inter/(union+1e-6) in f32.
      const float iou = (float)inter / ((float)uni + 1e-6f);
      const bool cand = (j != i) && (iou >= 0.1f);
      if (cand){
        any = true;
        const float uu = jax_uniform_2048((tid << 5) + j);
        const float g  = -logf(-logf(uu));
        if (g > best){ best = g; bestj = j; }            // first-max like argmax
      }
    }
    float nc0 = 0.f, nc1 = 0.f, nc2 = 0.f;
    if (any){
      nc0 = pos_coords[(b*32 + bestj)*3 + 0];
      nc1 = pos_coords[(b*32 + bestj)*3 + 1];
      nc2 = pos_coords[(b*32 + bestj)*3 + 2];
    }
    for (int e = 0; e < 128; ++e){
      float ne = nc0 * Wp[e*3+0];
      ne = fmaf(nc1, Wp[e*3+1], ne);
      ne = fmaf(nc2, Wp[e*3+2], ne);
      ne = ne + bp[e];                                   // == bp when invalid
      delta_l[tid*129 + e] = g_pe[tid*128 + e] - ne;
    }
  }
  __syncthreads();

  for (int idx = tid; idx < B_*I_*H_; idx += 256){
    const int row = idx >> 6, k = idx & 63;
    float s = 0.f;
    for (int e = 0; e < 128; ++e)
      s = fmaf(delta_l[row*129 + e], Wd1[k*128 + e], s);
    g_v2[idx] = s + bd1[k];
  }
}

// ---------------- K3: refined decode ----------------
__global__ void __launch_bounds__(256) dec_kernel(
    const float* __restrict__ Wd2, const float* __restrict__ bd2,
    float* __restrict__ out0)
{
  const int tid  = threadIdx.x;
  const int w_u  = __builtin_amdgcn_readfirstlane(tid >> 6);
  const int lane = tid & 63;
  const int bc   = blockIdx.x;           // 256 blocks
  const int b    = bc >> 7;
  const int nb   = (bc & 127) << 6;
  const int n    = nb + lane;
  const int p    = b * N_ + n;

  float u[64];
  #pragma unroll
  for (int k = 0; k < 64; ++k) u[k] = g_u[(size_t)k * BN_ + p];   // coalesced

  const float bd2v = bd2[0];
  for (int ii = 0; ii < 8; ++ii){
    const int i = w_u * 8 + ii;                       // wave-uniform
    const float* v = g_v2 + ((b * I_ + i) << 6);
    float acc = 0.f;
    #pragma unroll
    for (int k = 0; k < 64; ++k)
      acc = fmaf(Wd2[k], fmaxf(u[k] + v[k], 0.0f), acc);
    out0[(size_t)(b * I_ + i) * N_ + n] = acc + bd2v;
  }
}

// ---------------- launch ----------------
extern "C" void kernel_launch(void* const* d_in, const int* in_sizes, int n_in,
                              void* d_out, int out_size, void* d_ws, size_t ws_size,
                              hipStream_t stream)
{
  (void)in_sizes; (void)n_in; (void)out_size; (void)d_ws; (void)ws_size;
  const float* points     = (const float*)d_in[0];
  const float* pos_coords = (const float*)d_in[1];
  const float* W1  = (const float*)d_in[2];
  const float* A1  = (const float*)d_in[3];
  const float* B1  = (const float*)d_in[4];
  const float* W2  = (const float*)d_in[5];
  const float* A2  = (const float*)d_in[6];
  const float* B2  = (const float*)d_in[7];
  const float* Wp  = (const float*)d_in[8];
  const float* bp  = (const float*)d_in[9];
  const float* Wd1 = (const float*)d_in[10];
  const float* bd1 = (const float*)d_in[11];
  const float* Wd2 = (const float*)d_in[12];
  const float* bd2 = (const float*)d_in[13];

  float* out0   = (float*)d_out;                        // refined_logits [B,I,N]
  float* out_pf = out0 + (size_t)B_ * I_ * N_;          // point_feats   [B,N,E]

  prep_kernel<<<1, 256, 0, stream>>>(pos_coords, Wp, bp, Wd1, bd1);
  enc_kernel<<<256, 256, 0, stream>>>(points, W1, A1, B1, W2, A2, B2,
                                      Wd2, bd2, out_pf);
  inter_kernel<<<64, 256, 0, stream>>>();
  sample_kernel<<<1, 256, 0, stream>>>(pos_coords, Wp, bp, Wd1, bd1);
  dec_kernel<<<256, 256, 0, stream>>>(Wd2, bd2, out0);
}

// Round 10
// 211.015 us; speedup vs baseline: 3.9734x; 1.4091x over previous
//
#include <hip/hip_runtime.h>

// ---------------- problem constants ----------------
#define B_  2
#define N_  8192
#define I_  32
#define E_  128
#define H_  64
#define BN_ (B_*N_)          // 16384
#define NW_ (N_/64)          // 128 u64 words per (b,i) mask row

typedef unsigned long long u64;

// ---------------- module-scope device state (fully rewritten every launch) -----
__device__ float g_pe  [B_*I_*E_];     // pos_embed
__device__ float g_v1  [B_*I_*H_];     // decode hidden bias, initial
__device__ float g_v2  [B_*I_*H_];     // decode hidden bias, refined
__device__ float g_wd1t[E_*H_];        // Wd1 transposed [e][k]
__device__ float g_u   [H_*BN_];       // u[k][p] (4 MB, k-major -> coalesced)
__device__ u64   g_masks[B_*I_*NW_];   // initial masks as bitwords (64 KB)
__device__ int   g_inter[B_*I_*I_];    // intersection counts (diag = m_sum)

// ---------------- jax threefry2x32, key = key(42) = (0,42) ----------------
__device__ __forceinline__ unsigned rotl_(unsigned x, unsigned n){ return (x<<n)|(x>>(32u-n)); }

__device__ void threefry_42(unsigned x0, unsigned x1, unsigned* r0, unsigned* r1){
  const unsigned ks0 = 0u, ks1 = 42u, ks2 = 0x1BD11BDAu ^ 0u ^ 42u;
  x0 += ks0; x1 += ks1;
  x0+=x1; x1=rotl_(x1,13); x1^=x0;
  x0+=x1; x1=rotl_(x1,15); x1^=x0;
  x0+=x1; x1=rotl_(x1,26); x1^=x0;
  x0+=x1; x1=rotl_(x1, 6); x1^=x0;
  x0+=ks1; x1+=ks2+1u;
  x0+=x1; x1=rotl_(x1,17); x1^=x0;
  x0+=x1; x1=rotl_(x1,29); x1^=x0;
  x0+=x1; x1=rotl_(x1,16); x1^=x0;
  x0+=x1; x1=rotl_(x1,24); x1^=x0;
  x0+=ks2; x1+=ks0+2u;
  x0+=x1; x1=rotl_(x1,13); x1^=x0;
  x0+=x1; x1=rotl_(x1,15); x1^=x0;
  x0+=x1; x1=rotl_(x1,26); x1^=x0;
  x0+=x1; x1=rotl_(x1, 6); x1^=x0;
  x0+=ks0; x1+=ks1+3u;
  x0+=x1; x1=rotl_(x1,17); x1^=x0;
  x0+=x1; x1=rotl_(x1,29); x1^=x0;
  x0+=x1; x1=rotl_(x1,16); x1^=x0;
  x0+=x1; x1=rotl_(x1,24); x1^=x0;
  x0+=ks1; x1+=ks2+4u;
  x0+=x1; x1=rotl_(x1,13); x1^=x0;
  x0+=x1; x1=rotl_(x1,15); x1^=x0;
  x0+=x1; x1=rotl_(x1,26); x1^=x0;
  x0+=x1; x1=rotl_(x1, 6); x1^=x0;
  x0+=ks2; x1+=ks0+5u;
  *r0 = x0; *r1 = x1;
}

// element e of jax.random.uniform(key(42), (2,32,32), 1e-20, 1.0)
// PARTITIONABLE threefry (VERIFIED r7): counter (0,e), bits = out0 ^ out1.
__device__ float jax_uniform_2048(int e){
  unsigned o0, o1;
  threefry_42(0u, (unsigned)e, &o0, &o1);
  unsigned bits = o0 ^ o1;
  float u = __uint_as_float((bits >> 9) | 0x3f800000u) - 1.0f;
  u = u + 1e-20f;
  return fmaxf(1e-20f, u);
}

// ---------------- K0: pos_embed + Wd1^T + v1 (1 block) ----------------
__global__ void __launch_bounds__(256) prep_kernel(
    const float* __restrict__ pos_coords,
    const float* __restrict__ Wp, const float* __restrict__ bp,
    const float* __restrict__ Wd1,const float* __restrict__ bd1)
{
  __shared__ float t_l[E_*65];       // Wd1^T tile [e][k], pad 65: 33.3 KB
  const int tid = threadIdx.x;

  // coalesced read of Wd1 [k][e] -> LDS [e][k]
  for (int idx = tid; idx < H_*E_; idx += 256){
    int k = idx >> 7, e = idx & 127;           // lanes: e consecutive
    t_l[e*65 + k] = Wd1[idx];                  // stride-65 banks: conflict-free
  }
  for (int idx = tid; idx < B_*I_*E_; idx += 256){
    int row = idx >> 7, e = idx & 127;
    float s = pos_coords[row*3+0] * Wp[e*3+0];
    s = fmaf(pos_coords[row*3+1], Wp[e*3+1], s);
    s = fmaf(pos_coords[row*3+2], Wp[e*3+2], s);
    g_pe[idx] = s + bp[e];
  }
  __syncthreads();

  // coalesced write of g_wd1t [e][k]
  for (int idx = tid; idx < E_*H_; idx += 256){
    int e = idx >> 6, k = idx & 63;            // lanes: k consecutive
    g_wd1t[idx] = t_l[e*65 + k];
  }
  // v1[row][k]: wd1t from LDS (lane-coalesced k), pe wave-uniform (s_load)
  for (int idx = tid; idx < B_*I_*H_; idx += 256){
    int row = idx >> 6, k = idx & 63;
    float s = 0.f;
    for (int e = 0; e < 128; ++e)
      s = fmaf(g_pe[row*128 + e], t_l[e*65 + k], s);
    g_v1[idx] = s + bd1[k];
  }
}

// ---------------- K1: FUSED encoder + u + initial ballot ----------------
// 256 blocks x 256 threads; block = 64 consecutive points; wave w owns e-range
__global__ void __launch_bounds__(256) enc_kernel(
    const float* __restrict__ points,
    const float* __restrict__ W1, const float* __restrict__ A1,
    const float* __restrict__ B1, const float* __restrict__ W2,
    const float* __restrict__ A2, const float* __restrict__ B2,
    const float* __restrict__ Wd2,const float* __restrict__ bd2,
    float* __restrict__ out_pf)
{
  __shared__ float pf_l[E_*65];      // [e][point], padded: 33.3 KB
  __shared__ float u_l [64*65];      // [point][k], padded: 16.6 KB
  const int tid  = threadIdx.x;
  const int w_u  = __builtin_amdgcn_readfirstlane(tid >> 6);
  const int lane = tid & 63;
  const int p0   = blockIdx.x * 64;
  const int p    = p0 + lane;
  const int b    = blockIdx.x >> 7;            // 128 blocks per batch

  const float x0 = points[p*3+0];
  const float x1 = points[p*3+1];
  const float x2 = points[p*3+2];

  float a1[4];
  #pragma unroll
  for (int r = 0; r < 4; ++r){
    float s = x0 * A1[r*3+0];
    s = fmaf(x1, A1[r*3+1], s);
    s = fmaf(x2, A1[r*3+2], s);
    a1[r] = s;
  }
  float t1[64];
  #pragma unroll
  for (int k = 0; k < 64; ++k){
    float s = x0 * W1[k*3+0];
    s = fmaf(x1, W1[k*3+1], s);
    s = fmaf(x2, W1[k*3+2], s);
    float l = a1[0] * B1[k*4+0];
    l = fmaf(a1[1], B1[k*4+1], l);
    l = fmaf(a1[2], B1[k*4+2], l);
    l = fmaf(a1[3], B1[k*4+3], l);
    t1[k] = fmaxf(fmaf(0.25f, l, s), 0.0f);
  }
  float a2[4];
  #pragma unroll
  for (int r = 0; r < 4; ++r){
    float s = 0.f;
    #pragma unroll
    for (int j = 0; j < 64; ++j) s = fmaf(t1[j], A2[r*64+j], s);
    a2[r] = s;
  }
  float u_p[64];
  #pragma unroll
  for (int k = 0; k < 64; ++k) u_p[k] = 0.f;

  for (int ei = 0; ei < 32; ++ei){
    const int e = w_u * 32 + ei;               // wave-uniform -> scalar loads
    float s1 = 0.f;
    #pragma unroll
    for (int j = 0; j < 64; ++j) s1 = fmaf(t1[j], W2[e*64+j], s1);
    float s2 = a2[0] * B2[e*4+0];
    s2 = fmaf(a2[1], B2[e*4+1], s2);
    s2 = fmaf(a2[2], B2[e*4+2], s2);
    s2 = fmaf(a2[3], B2[e*4+3], s2);
    const float pf = fmaf(0.25f, s2, s1);
    pf_l[e*65 + lane] = pf;                    // bank = lane%32: conflict-free
    #pragma unroll
    for (int k = 0; k < 64; ++k) u_p[k] = fmaf(pf, g_wd1t[e*64+k], u_p[k]);
  }
  __syncthreads();

  // coalesced pf store
  for (int idx = tid; idx < 64*E_; idx += 256){
    const int pt = idx >> 7, e = idx & 127;
    out_pf[(size_t)p0 * E_ + idx] = pf_l[e*65 + pt];
  }

  // staged reduction of the 4 e-range partials into u_l[point][k]
  for (int pass = 0; pass < 4; ++pass){
    if (w_u == pass){
      if (pass == 0){
        #pragma unroll
        for (int k = 0; k < 64; ++k) u_l[lane*65 + k] = u_p[k];
      } else {
        #pragma unroll
        for (int k = 0; k < 64; ++k) u_l[lane*65 + k] += u_p[k];
      }
    }
    __syncthreads();
  }

  // coalesced u store: k-major
  for (int idx = tid; idx < 64*64; idx += 256){
    const int k = idx >> 6, pl = idx & 63;
    g_u[(size_t)k * BN_ + p0 + pl] = u_l[pl*65 + k];
  }

  // fused initial decode + ballot
  const float bd2v = bd2[0];
  for (int ii = 0; ii < 8; ++ii){
    const int i = w_u * 8 + ii;                          // wave-uniform
    const float* v = g_v1 + ((b * I_ + i) << 6);
    float acc = 0.f;
    #pragma unroll
    for (int k = 0; k < 64; ++k)
      acc = fmaf(Wd2[k], fmaxf(u_l[lane*65 + k] + v[k], 0.0f), acc);
    const float logit = acc + bd2v;
    u64 bal = __ballot(logit > 0.0f);
    if (lane == 0) g_masks[(size_t)(b * I_ + i) * NW_ + (blockIdx.x & 127)] = bal;
  }
}

// ---------------- K2a: inter[r][j] = popcount(m_r & m_j), 64 blocks ----------------
__global__ void __launch_bounds__(256) inter_kernel()
{
  const int r   = blockIdx.x;          // 0..63
  const int b   = r >> 5;
  const int tid = threadIdx.x;
  const int j   = tid >> 3;            // 0..31
  const int ws  = (tid & 7) * 16;      // word segment base
  const u64* mi = g_masks + (size_t)r * NW_;
  const u64* mj = g_masks + (size_t)(b*32 + j) * NW_;
  int s = 0;
  #pragma unroll
  for (int w = 0; w < 16; ++w)
    s += __popcll(mi[ws + w] & mj[ws + w]);
  s += __shfl_xor(s, 1, 64);
  s += __shfl_xor(s, 2, 64);
  s += __shfl_xor(s, 4, 64);
  if ((tid & 7) == 0) g_inter[r*32 + j] = s;
}

// ---------------- K2b: Gumbel-max sampling + v2 (1 block) ----------------
__global__ void __launch_bounds__(256) sample_kernel(
    const float* __restrict__ pos_coords,
    const float* __restrict__ Wp, const float* __restrict__ bp,
    const float* __restrict__ bd1)
{
  __shared__ int   inter_l[2048];
  __shared__ float delta_l[64*129];
  __shared__ float nc_l[64][3];
  const int tid = threadIdx.x;

  for (int idx = tid; idx < 2048; idx += 256) inter_l[idx] = g_inter[idx];
  __syncthreads();

  // phase 1: per-row Gumbel-max pick -> nc into LDS
  if (tid < 64){
    const int b = tid >> 5;
    const int i = tid & 31;
    const int msum_i = inter_l[(b << 10) + (i << 5) + i];   // diag = m_sum
    float best = -INFINITY; int bestj = 0; bool any = false;
    for (int j = 0; j < 32; ++j){
      const int inter = inter_l[(b << 10) + (i << 5) + j];
      const int msum_j = inter_l[(b << 10) + (j << 5) + j];
      const int uni   = msum_i + msum_j - inter;
      // EXACT f32 mimicry of the reference: inter/(union+1e-6) in f32.
      const float iou = (float)inter / ((float)uni + 1e-6f);
      const bool cand = (j != i) && (iou >= 0.1f);
      if (cand){
        any = true;
        const float uu = jax_uniform_2048((tid << 5) + j);
        const float g  = -logf(-logf(uu));
        if (g > best){ best = g; bestj = j; }            // first-max like argmax
      }
    }
    nc_l[tid][0] = any ? pos_coords[(b*32 + bestj)*3 + 0] : 0.f;
    nc_l[tid][1] = any ? pos_coords[(b*32 + bestj)*3 + 1] : 0.f;
    nc_l[tid][2] = any ? pos_coords[(b*32 + bestj)*3 + 2] : 0.f;
  }
  __syncthreads();

  // phase 2: delta[row][e] coalesced across e (lanes consecutive)
  for (int idx = tid; idx < 64*E_; idx += 256){
    const int row = idx >> 7, e = idx & 127;
    float ne = nc_l[row][0] * Wp[e*3+0];
    ne = fmaf(nc_l[row][1], Wp[e*3+1], ne);
    ne = fmaf(nc_l[row][2], Wp[e*3+2], ne);
    ne = ne + bp[e];                                     // == bp when invalid
    delta_l[row*129 + e] = g_pe[row*128 + e] - ne;
  }
  __syncthreads();

  // phase 3: v2[row][k] with lane-coalesced wd1t reads
  for (int idx = tid; idx < B_*I_*H_; idx += 256){
    const int row = idx >> 6, k = idx & 63;
    float s = 0.f;
    for (int e = 0; e < 128; ++e)
      s = fmaf(delta_l[row*129 + e], g_wd1t[e*64 + k], s);
    g_v2[idx] = s + bd1[k];
  }
}

// ---------------- K3: refined decode ----------------
__global__ void __launch_bounds__(256) dec_kernel(
    const float* __restrict__ Wd2, const float* __restrict__ bd2,
    float* __restrict__ out0)
{
  const int tid  = threadIdx.x;
  const int w_u  = __builtin_amdgcn_readfirstlane(tid >> 6);
  const int lane = tid & 63;
  const int bc   = blockIdx.x;           // 256 blocks
  const int b    = bc >> 7;
  const int nb   = (bc & 127) << 6;
  const int n    = nb + lane;
  const int p    = b * N_ + n;

  float u[64];
  #pragma unroll
  for (int k = 0; k < 64; ++k) u[k] = g_u[(size_t)k * BN_ + p];   // coalesced

  const float bd2v = bd2[0];
  for (int ii = 0; ii < 8; ++ii){
    const int i = w_u * 8 + ii;                       // wave-uniform
    const float* v = g_v2 + ((b * I_ + i) << 6);
    float acc = 0.f;
    #pragma unroll
    for (int k = 0; k < 64; ++k)
      acc = fmaf(Wd2[k], fmaxf(u[k] + v[k], 0.0f), acc);
    out0[(size_t)(b * I_ + i) * N_ + n] = acc + bd2v;
  }
}

// ---------------- launch ----------------
extern "C" void kernel_launch(void* const* d_in, const int* in_sizes, int n_in,
                              void* d_out, int out_size, void* d_ws, size_t ws_size,
                              hipStream_t stream)
{
  (void)in_sizes; (void)n_in; (void)out_size; (void)d_ws; (void)ws_size;
  const float* points     = (const float*)d_in[0];
  const float* pos_coords = (const float*)d_in[1];
  const float* W1  = (const float*)d_in[2];
  const float* A1  = (const float*)d_in[3];
  const float* B1  = (const float*)d_in[4];
  const float* W2  = (const float*)d_in[5];
  const float* A2  = (const float*)d_in[6];
  const float* B2  = (const float*)d_in[7];
  const float* Wp  = (const float*)d_in[8];
  const float* bp  = (const float*)d_in[9];
  const float* Wd1 = (const float*)d_in[10];
  const float* bd1 = (const float*)d_in[11];
  const float* Wd2 = (const float*)d_in[12];
  const float* bd2 = (const float*)d_in[13];

  float* out0   = (float*)d_out;                        // refined_logits [B,I,N]
  float* out_pf = out0 + (size_t)B_ * I_ * N_;          // point_feats   [B,N,E]

  prep_kernel<<<1, 256, 0, stream>>>(pos_coords, Wp, bp, Wd1, bd1);
  enc_kernel<<<256, 256, 0, stream>>>(points, W1, A1, B1, W2, A2, B2,
                                      Wd2, bd2, out_pf);
  inter_kernel<<<64, 256, 0, stream>>>();
  sample_kernel<<<1, 256, 0, stream>>>(pos_coords, Wp, bp, bd1);
  dec_kernel<<<256, 256, 0, stream>>>(Wd2, bd2, out0);
}